// Round 1
// baseline (217.147 us; speedup 1.0000x reference)
//
#include <hip/hip_runtime.h>

#define BB 8
#define NN 8192
#define SS 2048
#define CC 64
#define NS 32
#define COUT 67   // 3 xyz + 64 feature channels

__global__ __launch_bounds__(256) void qg_kernel(
    const float* __restrict__ xyz,      // (B, N, 3)
    const float* __restrict__ new_xyz,  // (B, S, 3)
    const float* __restrict__ feat,     // (B, N, C)
    float* __restrict__ out)            // (B, 67, S, NS)
{
#pragma clang fp contract(off)
    __shared__ int idx_sh[4][NS];
    const int wave = threadIdx.x >> 6;
    const int lane = threadIdx.x & 63;
    const int qid  = blockIdx.x * 4 + wave;   // 0 .. B*S-1
    const int b = qid >> 11;                  // / 2048
    const int s = qid & 2047;

    // R2: f32 nearest to 0.2*0.2 (python double) == 0.04f; strict '<' to match
    // weak-scalar f32 comparison semantics of the reference.
    const float R2 = 0.04f;

    const float* ctr = new_xyz + ((size_t)b * SS + s) * 3;
    const float cx = ctr[0], cy = ctr[1], cz = ctr[2];

    const float* xb = xyz + (size_t)b * NN * 3;

    // ---- ball query: wave-cooperative scan, 64 points per chunk ----
    int total = 0;      // wave-uniform count of hits so far
    int firstIdx = 0;   // wave-uniform first hit index
    for (int j0 = 0; j0 < NN && total < NS; j0 += 64) {
        const int j = j0 + lane;
        const float* p = xb + (size_t)j * 3;
        const float dx = p[0] - cx;
        const float dy = p[1] - cy;
        const float dz = p[2] - cz;
        float d2 = dx * dx;
        d2 = d2 + dy * dy;
        d2 = d2 + dz * dz;          // ((dx^2 + dy^2) + dz^2), no fma contraction
        const bool hit = d2 < R2;
        const unsigned long long mask = __ballot(hit);
        if (total == 0 && mask != 0ull)
            firstIdx = j0 + __builtin_ctzll(mask);
        if (hit) {
            const int pos = total + __popcll(mask & ((1ull << lane) - 1ull));
            if (pos < NS) idx_sh[wave][pos] = j;
        }
        total += __popcll(mask);
    }
    // fill semantics of the reference: pad with first hit, or 0 if no hits
    if (total < NS) {
        const int fill = (total > 0) ? firstIdx : 0;
        if (lane >= total && lane < NS) idx_sh[wave][lane] = fill;
    }
    // producer == consumer wave: no barrier needed (compiler inserts lgkmcnt)

    // ---- gather + transpose write ----
    const int k = lane & 31;        // sample slot
    const int h = lane >> 5;        // half-wave selector
    const int ik = idx_sh[wave][k];

    const size_t plane = (size_t)SS * NS;

    // channels 0..2: grouped_xyz - center (half-wave does it; 3 of 67 channels)
    if (h == 0) {
        const float* p = xb + (size_t)ik * 3;
        const size_t ob = (((size_t)b * COUT + 0) * SS + s) * NS + k;
        out[ob]             = p[0] - cx;
        out[ob + plane]     = p[1] - cy;
        out[ob + 2 * plane] = p[2] - cz;
    }

    // channels 3..66: grouped features. Each lane float4-loads 16B of its row;
    // lanes (k, k+32) cover 8 channels per iteration. Stores: each instr writes
    // two contiguous 128B segments (k=0..31 per channel plane) -> coalesced.
    const float* frow = feat + ((size_t)b * NN + ik) * CC;
    const size_t obase = (((size_t)b * COUT + 3) * SS + s) * NS + k;
    for (int cf = 0; cf < CC; cf += 8) {
        const int c0 = cf + 4 * h;
        const float4 f = *(const float4*)(frow + c0);
        const size_t o = obase + (size_t)c0 * plane;
        out[o]             = f.x;
        out[o + plane]     = f.y;
        out[o + 2 * plane] = f.z;
        out[o + 3 * plane] = f.w;
    }
}

extern "C" void kernel_launch(void* const* d_in, const int* in_sizes, int n_in,
                              void* d_out, int out_size, void* d_ws, size_t ws_size,
                              hipStream_t stream) {
    const float* xyz     = (const float*)d_in[0];
    const float* new_xyz = (const float*)d_in[1];
    const float* feat    = (const float*)d_in[2];
    float* out = (float*)d_out;
    // one wave per query, 4 waves per block: B*S / 4 = 4096 blocks
    qg_kernel<<<dim3((BB * SS) / 4), dim3(256), 0, stream>>>(xyz, new_xyz, feat, out);
}

// Round 2
// 195.980 us; speedup vs baseline: 1.1080x; 1.1080x over previous
//
#include <hip/hip_runtime.h>

#define BB 8
#define NN 8192
#define SS 2048
#define CC 64
#define NS 32
#define COUT 67   // 3 xyz + 64 feature channels

// ---------------- Kernel A: ball-query scan, one wave per query ----------------
// Unrolled 4x64 = 256 points per latency chain: 12 independent global loads are
// issued before the 4 dependent ballot/popcount steps, so L2 latency (~200 cyc)
// is paid once per 256 points instead of once per 64.
__global__ __launch_bounds__(256) void scan_kernel(
    const float* __restrict__ xyz,      // (B, N, 3)
    const float* __restrict__ new_xyz,  // (B, S, 3)
    int* __restrict__ idx_ws)           // (B*S, NS)
{
#pragma clang fp contract(off)
    const int wave = threadIdx.x >> 6;
    const int lane = threadIdx.x & 63;
    const int qid  = blockIdx.x * 4 + wave;
    const int b = qid >> 11;
    const int s = qid & 2047;

    const float R2 = 0.04f;   // f32 nearest of 0.2*0.2; strict '<' matches ref

    const float* ctr = new_xyz + ((size_t)b * SS + s) * 3;
    const float cx = ctr[0], cy = ctr[1], cz = ctr[2];
    const float* xb = xyz + (size_t)b * NN * 3;

    int* myidx = idx_ws + (size_t)qid * NS;
    const unsigned long long lt = (1ull << lane) - 1ull;

    int total = 0;
    int firstIdx = -1;
    for (int j0 = 0; j0 < NN && total < NS; j0 += 256) {
        float d2v[4];
#pragma unroll
        for (int u = 0; u < 4; ++u) {
            const int j = j0 + u * 64 + lane;
            const float* p = xb + (size_t)j * 3;
            const float dx = p[0] - cx;
            const float dy = p[1] - cy;
            const float dz = p[2] - cz;
            float d2 = dx * dx;
            d2 = d2 + dy * dy;
            d2 = d2 + dz * dz;       // ((dx^2+dy^2)+dz^2), no fma contraction
            d2v[u] = d2;
        }
#pragma unroll
        for (int u = 0; u < 4; ++u) {
            const bool hit = d2v[u] < R2;
            const unsigned long long mask = __ballot(hit);
            if (firstIdx < 0 && mask != 0ull)
                firstIdx = j0 + u * 64 + __builtin_ctzll(mask);
            if (hit) {
                const int pos = total + __popcll(mask & lt);
                if (pos < NS) myidx[pos] = j0 + u * 64 + lane;
            }
            total += __popcll(mask);
        }
    }
    if (total < NS) {
        const int fill = (total > 0) ? firstIdx : 0;
        if (lane >= total && lane < NS) myidx[lane] = fill;
    }
}

// ---------------- Kernel B: gather + transpose, pure bandwidth ----------------
// One wave per query, uniform length -> no imbalance; stores stream to HBM.
__global__ __launch_bounds__(256) void gather_kernel(
    const float* __restrict__ xyz,
    const float* __restrict__ new_xyz,
    const float* __restrict__ feat,     // (B, N, C)
    const int* __restrict__ idx_ws,     // (B*S, NS)
    float* __restrict__ out)            // (B, 67, S, NS)
{
#pragma clang fp contract(off)
    const int wave = threadIdx.x >> 6;
    const int lane = threadIdx.x & 63;
    const int qid  = blockIdx.x * 4 + wave;
    const int b = qid >> 11;
    const int s = qid & 2047;

    const int k = lane & 31;   // sample slot
    const int h = lane >> 5;   // half-wave selector

    const int ik = idx_ws[(size_t)qid * NS + k];   // both halves load same 128B

    const float* ctr = new_xyz + ((size_t)b * SS + s) * 3;
    const float cx = ctr[0], cy = ctr[1], cz = ctr[2];
    const float* xb = xyz + (size_t)b * NN * 3;

    const size_t plane = (size_t)SS * NS;

    // channels 0..2: grouped_xyz - center
    if (h == 0) {
        const float* p = xb + (size_t)ik * 3;
        const size_t ob = (((size_t)b * COUT + 0) * SS + s) * NS + k;
        out[ob]             = p[0] - cx;
        out[ob + plane]     = p[1] - cy;
        out[ob + 2 * plane] = p[2] - cz;
    }

    // channels 3..66: each lane float4-loads 16B of its row; lanes (k, k+32)
    // cover 8 channels/iter. Each store instr writes 2 contiguous 128B segs.
    const float* frow = feat + ((size_t)b * NN + ik) * CC;
    const size_t obase = (((size_t)b * COUT + 3) * SS + s) * NS + k;
    for (int cf = 0; cf < CC; cf += 8) {
        const int c0 = cf + 4 * h;
        const float4 f = *(const float4*)(frow + c0);
        const size_t o = obase + (size_t)c0 * plane;
        out[o]             = f.x;
        out[o + plane]     = f.y;
        out[o + 2 * plane] = f.z;
        out[o + 3 * plane] = f.w;
    }
}

extern "C" void kernel_launch(void* const* d_in, const int* in_sizes, int n_in,
                              void* d_out, int out_size, void* d_ws, size_t ws_size,
                              hipStream_t stream) {
    const float* xyz     = (const float*)d_in[0];
    const float* new_xyz = (const float*)d_in[1];
    const float* feat    = (const float*)d_in[2];
    float* out = (float*)d_out;
    int* idx_ws = (int*)d_ws;   // B*S*NS ints = 2 MB

    scan_kernel<<<dim3((BB * SS) / 4), dim3(256), 0, stream>>>(xyz, new_xyz, idx_ws);
    gather_kernel<<<dim3((BB * SS) / 4), dim3(256), 0, stream>>>(xyz, new_xyz, feat, idx_ws, out);
}